// Round 1
// baseline (444.872 us; speedup 1.0000x reference)
//
#include <hip/hip_runtime.h>

// Problem constants
#define BB 2
#define SS 2048
#define DD 2048
#define HH 16
#define HDIM 128
#define QD (3*DD)        // row stride of fused qkv output
#define MTOK (BB*SS)     // 4096 token rows
#define BHH (BB*HH)      // 32 (b,h) pairs
#define NCHUNK 16        // scan chunks per (b,h): 2048/128

typedef __attribute__((ext_vector_type(8))) __bf16 bf16x8;
typedef __attribute__((ext_vector_type(4))) float f32x4;

__device__ __forceinline__ unsigned short f2bf(float f) {
  unsigned u = __float_as_uint(f);
  u += 0x7FFFu + ((u >> 16) & 1u);   // RNE
  return (unsigned short)(u >> 16);
}
__device__ __forceinline__ float bf2f(unsigned short s) {
  return __uint_as_float(((unsigned)s) << 16);
}

// async global->LDS, 16B per lane; dst must be wave-uniform base (HW adds lane*16)
#define GLOAD_LDS16(src, dst)                                                   \
  __builtin_amdgcn_global_load_lds(                                             \
      (const void __attribute__((address_space(1)))*)(src),                     \
      (void __attribute__((address_space(3)))*)(dst), 16, 0, 0)

// ---------------- fp32 -> bf16 convert (vectorized x4) ----------------
__global__ void cvt_f32_bf16(const float* __restrict__ in,
                             unsigned short* __restrict__ out, int n4) {
  int i = blockIdx.x * blockDim.x + threadIdx.x;
  if (i < n4) {
    float4 v = ((const float4*)in)[i];
    ushort4 o;
    o.x = f2bf(v.x); o.y = f2bf(v.y); o.z = f2bf(v.z); o.w = f2bf(v.w);
    ((ushort4*)out)[i] = o;
  }
}

__global__ void concat3(const float* __restrict__ a, const float* __restrict__ b,
                        const float* __restrict__ c, float* __restrict__ out) {
  int i = blockIdx.x * blockDim.x + threadIdx.x;
  if (i < DD) { out[i] = a[i]; out[DD + i] = b[i]; out[2 * DD + i] = c[i]; }
}

// ---------------- bf16 GEMM: C[M][N] = A[M][K] @ W[N][K]^T + bias[N] ----------------
// m97-style: 128x128 tile, BK=32, 4 waves in 2x2 quadrants, 16x16x32 bf16 MFMA.
template <bool OUT_BF16>
__global__ __launch_bounds__(256, 2) void gemm_bt(
    const __bf16* __restrict__ A, const __bf16* __restrict__ W,
    const float* __restrict__ bias, void* __restrict__ Cout,
    int M, int N, int K) {
  __shared__ __bf16 lA[128 * 32];  // 8 KB, row-major [128][32], no pad (global_load_lds)
  __shared__ __bf16 lB[128 * 32];
  const int t = threadIdx.x;
  const int lane = t & 63, wave = t >> 6;
  const int quad = lane >> 4, l16 = lane & 15;
  const int m0 = blockIdx.y * 128, n0 = blockIdx.x * 128;
  const int wm = (wave & 1) * 64, wn = (wave >> 1) * 64;

  f32x4 acc[4][4] = {};

  for (int k0 = 0; k0 < K; k0 += 32) {
#pragma unroll
    for (int c = 0; c < 2; ++c) {
      int lin = c * 256 + t;          // 16B-chunk id, 4 chunks per 32-col row
      int row = lin >> 2;
      int col = (lin & 3) * 8;
      const __bf16* srcA = A + (size_t)(m0 + row) * K + k0 + col;
      const __bf16* srcB = W + (size_t)(n0 + row) * K + k0 + col;
      GLOAD_LDS16(srcA, &lA[(c * 256 + wave * 64) * 8]);
      GLOAD_LDS16(srcB, &lB[(c * 256 + wave * 64) * 8]);
    }
    __syncthreads();  // drains vmcnt -> LDS tile ready
    bf16x8 af[4], bfr[4];
#pragma unroll
    for (int mt = 0; mt < 4; ++mt)
      af[mt] = *(const bf16x8*)&lA[(wm + mt * 16 + l16) * 32 + quad * 8];
#pragma unroll
    for (int nt = 0; nt < 4; ++nt)
      bfr[nt] = *(const bf16x8*)&lB[(wn + nt * 16 + l16) * 32 + quad * 8];
#pragma unroll
    for (int mt = 0; mt < 4; ++mt)
#pragma unroll
      for (int nt = 0; nt < 4; ++nt)
        acc[mt][nt] = __builtin_amdgcn_mfma_f32_16x16x32_bf16(af[mt], bfr[nt],
                                                              acc[mt][nt], 0, 0, 0);
    __syncthreads();  // protect LDS before next stage
  }

  // epilogue: C/D layout col=lane&15, row=quad*4+reg  [m89/m91 verified]
#pragma unroll
  for (int mt = 0; mt < 4; ++mt) {
#pragma unroll
    for (int nt = 0; nt < 4; ++nt) {
      int col = n0 + wn + nt * 16 + l16;
      float bv = bias[col];
#pragma unroll
      for (int r = 0; r < 4; ++r) {
        int row = m0 + wm + mt * 16 + quad * 4 + r;
        float v = acc[mt][nt][r] + bv;
        if constexpr (OUT_BF16)
          ((unsigned short*)Cout)[(size_t)row * N + col] = f2bf(v);
        else
          ((float*)Cout)[(size_t)row * N + col] = v;
      }
    }
  }
}

// ---------------- QK^T upper-triangle exp row-sums + diagonal ----------------
// grid: (SS/64, BHH). Each block: 64 i-rows (wave w owns 16), j-tiles of 128 from
// the (128-aligned) diagonal to S. denom[i] = i + sum_{j>=i} exp(s_ij*scale).
__global__ __launch_bounds__(256, 2) void qk_rowsum(
    const __bf16* __restrict__ q0, const __bf16* __restrict__ k0,
    float* __restrict__ denom, float* __restrict__ diag) {
  // LDS layout [ks=4][row=128][32] so fragment reads have 64B row stride
  __shared__ __bf16 lK[4 * 128 * 32];  // 32 KB
  const int t = threadIdx.x;
  const int lane = t & 63, wave = t >> 6;
  const int quad = lane >> 4, l16 = lane & 15;
  const int bh = blockIdx.y;
  const int b = bh >> 4, h = bh & 15;
  const int i0 = blockIdx.x * 64;
  const int rowg = i0 + wave * 16;  // wave's rows: rowg + (0..15)
  const float scale = 0.02209708691207961f;  // 1/sqrt(2048)

  // Q fragments for this wave's 16 rows, all 4 k-steps (K=HDIM=128), kept in regs
  bf16x8 af[4];
  const __bf16* qbase = q0 + (size_t)(b * SS + rowg + l16) * QD + h * HDIM;
#pragma unroll
  for (int ks = 0; ks < 4; ++ks)
    af[ks] = *(const bf16x8*)(qbase + ks * 32 + quad * 8);

  float rowsum[4] = {0.f, 0.f, 0.f, 0.f};
  float diagv[4] = {0.f, 0.f, 0.f, 0.f};

  for (int j0 = i0 & ~127; j0 < SS; j0 += 128) {
    // stage K-tile [128 rows][128 k] into [ks][row][32] layout
#pragma unroll
    for (int c = 0; c < 8; ++c) {
      int L = c * 256 + t;        // 16B-chunk id, 2048 total
      int ks = L >> 9;            // 512 chunks per ks-slice
      int rem = L & 511;
      int row = rem >> 2;
      int c4 = rem & 3;
      const __bf16* src =
          k0 + (size_t)(b * SS + j0 + row) * QD + h * HDIM + ks * 32 + c4 * 8;
      GLOAD_LDS16(src, &lK[(c * 256 + wave * 64) * 8]);
    }
    __syncthreads();
#pragma unroll
    for (int nt = 0; nt < 8; ++nt) {
      f32x4 acc = {0.f, 0.f, 0.f, 0.f};
#pragma unroll
      for (int ks = 0; ks < 4; ++ks) {
        bf16x8 bfr =
            *(const bf16x8*)&lK[ks * 4096 + (nt * 16 + l16) * 32 + quad * 8];
        acc = __builtin_amdgcn_mfma_f32_16x16x32_bf16(af[ks], bfr, acc, 0, 0, 0);
      }
      int colg = j0 + nt * 16 + l16;
#pragma unroll
      for (int r = 0; r < 4; ++r) {
        int rg = rowg + quad * 4 + r;
        if (colg >= rg) {
          float e = __expf(acc[r] * scale);
          rowsum[r] += e;
          if (colg == rg) diagv[r] = e;
        }
      }
    }
    __syncthreads();
  }

  // reduce over the 16 column-lanes (lanes quad*16 .. quad*16+15)
#pragma unroll
  for (int r = 0; r < 4; ++r) {
    float s = rowsum[r], d = diagv[r];
#pragma unroll
    for (int off = 1; off < 16; off <<= 1) {
      s += __shfl_xor(s, off, 64);
      d += __shfl_xor(d, off, 64);
    }
    if (l16 == 0) {
      int rg = rowg + quad * 4 + r;
      denom[bh * SS + rg] = (float)rg + s;
      diag[bh * SS + rg] = d;
    }
  }
}

// ---------------- V prefix-scan, two-pass ----------------
// pass1: per-chunk sums. grid = BHH*NCHUNK blocks, 128 threads (one per dim)
__global__ void scan_pass1(const __bf16* __restrict__ v0,
                           float* __restrict__ csum) {
  int blk = blockIdx.x;
  int bh = blk >> 4, c = blk & 15;
  int b = bh >> 4, h = bh & 15;
  int d = threadIdx.x;
  const unsigned short* base =
      (const unsigned short*)v0 + (size_t)(b * SS + c * 128) * QD + h * HDIM + d;
  float s = 0.f;
#pragma unroll 8
  for (int i = 0; i < 128; ++i) s += bf2f(base[(size_t)i * QD]);
  csum[(size_t)blk * 128 + d] = s;
}

// pass2: scan within chunk, write ctx = (prefix_excl + diag*v)/denom (bf16)
__global__ void scan_pass2(const __bf16* __restrict__ v0,
                           const float* __restrict__ csum,
                           const float* __restrict__ denom,
                           const float* __restrict__ diag,
                           unsigned short* __restrict__ ctx) {
  int blk = blockIdx.x;
  int bh = blk >> 4, c = blk & 15;
  int b = bh >> 4, h = bh & 15;
  int d = threadIdx.x;
  float acc = 0.f;
  for (int cc = 0; cc < c; ++cc) acc += csum[(size_t)(bh * 16 + cc) * 128 + d];
  const unsigned short* vbase =
      (const unsigned short*)v0 + (size_t)(b * SS + c * 128) * QD + h * HDIM + d;
  unsigned short* obase = ctx + (size_t)(b * SS + c * 128) * DD + h * HDIM + d;
  const float* dn = denom + bh * SS + c * 128;
  const float* dg = diag + bh * SS + c * 128;
#pragma unroll 4
  for (int i = 0; i < 128; ++i) {
    float vd = bf2f(vbase[(size_t)i * QD]);
    float o = (acc + dg[i] * vd) / dn[i];
    obase[(size_t)i * DD] = f2bf(o);
    acc += vd;
  }
}

extern "C" void kernel_launch(void* const* d_in, const int* in_sizes, int n_in,
                              void* d_out, int out_size, void* d_ws, size_t ws_size,
                              hipStream_t stream) {
  (void)in_sizes; (void)n_in; (void)out_size; (void)ws_size;
  const float* x    = (const float*)d_in[0];
  const float* wq_w = (const float*)d_in[1];
  const float* wq_b = (const float*)d_in[2];
  const float* wk_w = (const float*)d_in[3];
  const float* wk_b = (const float*)d_in[4];
  const float* wv_w = (const float*)d_in[5];
  const float* wv_b = (const float*)d_in[6];
  const float* wo_w = (const float*)d_in[7];
  const float* wo_b = (const float*)d_in[8];

  char* ws = (char*)d_ws;
  size_t off = 0;
  auto alloc = [&](size_t bytes) {
    char* p = ws + off;
    off += (bytes + 255) & ~(size_t)255;
    return p;
  };
  unsigned short* xb    = (unsigned short*)alloc((size_t)MTOK * DD * 2);   // 16 MB
  unsigned short* wqkvb = (unsigned short*)alloc((size_t)3 * DD * DD * 2); // 24 MB
  unsigned short* wob   = (unsigned short*)alloc((size_t)DD * DD * 2);     // 8 MB
  unsigned short* qkv   = (unsigned short*)alloc((size_t)MTOK * QD * 2);   // 48 MB
  unsigned short* ctx   = (unsigned short*)alloc((size_t)MTOK * DD * 2);   // 16 MB
  float* biasqkv = (float*)alloc((size_t)3 * DD * 4);
  float* denom   = (float*)alloc((size_t)BHH * SS * 4);
  float* diag    = (float*)alloc((size_t)BHH * SS * 4);
  float* csum    = (float*)alloc((size_t)BHH * NCHUNK * 128 * 4);

  // 1) converts
  {
    int n4 = MTOK * DD / 4;
    cvt_f32_bf16<<<n4 / 256, 256, 0, stream>>>(x, xb, n4);
    int w4 = DD * DD / 4;
    cvt_f32_bf16<<<w4 / 256, 256, 0, stream>>>(wq_w, wqkvb, w4);
    cvt_f32_bf16<<<w4 / 256, 256, 0, stream>>>(wk_w, wqkvb + (size_t)DD * DD, w4);
    cvt_f32_bf16<<<w4 / 256, 256, 0, stream>>>(wv_w, wqkvb + (size_t)2 * DD * DD, w4);
    cvt_f32_bf16<<<w4 / 256, 256, 0, stream>>>(wo_w, wob, w4);
    concat3<<<(DD + 255) / 256, 256, 0, stream>>>(wq_b, wk_b, wv_b, biasqkv);
  }

  // 2) fused QKV GEMM: [4096,2048] x [6144,2048]^T -> qkv bf16 [4096][6144]
  gemm_bt<true><<<dim3(QD / 128, MTOK / 128), 256, 0, stream>>>(
      (const __bf16*)xb, (const __bf16*)wqkvb, biasqkv, qkv, MTOK, QD, DD);

  // 3) denominators + diagonal exps
  qk_rowsum<<<dim3(SS / 64, BHH), 256, 0, stream>>>(
      (const __bf16*)qkv,                 // q at col 0
      (const __bf16*)qkv + DD,            // k at col 2048
      denom, diag);

  // 4) V scan -> ctx
  scan_pass1<<<BHH * NCHUNK, 128, 0, stream>>>((const __bf16*)qkv + 2 * DD, csum);
  scan_pass2<<<BHH * NCHUNK, 128, 0, stream>>>((const __bf16*)qkv + 2 * DD, csum,
                                               denom, diag, ctx);

  // 5) output projection: [4096,2048] x [2048,2048]^T -> d_out fp32
  gemm_bt<false><<<dim3(DD / 128, MTOK / 128), 256, 0, stream>>>(
      (const __bf16*)ctx, (const __bf16*)wob, wo_b, d_out, MTOK, DD, DD);
}

// Round 2
// 408.011 us; speedup vs baseline: 1.0903x; 1.0903x over previous
//
#include <hip/hip_runtime.h>

// Problem constants
#define BB 2
#define SS 2048
#define DD 2048
#define HH 16
#define HDIM 128
#define QD (3*DD)        // row stride of fused qkv output
#define MTOK (BB*SS)     // 4096 token rows
#define BHH (BB*HH)      // 32 (b,h) pairs
#define NCHUNK 16        // scan chunks per (b,h): 2048/128

typedef __attribute__((ext_vector_type(8))) __bf16 bf16x8;
typedef __attribute__((ext_vector_type(4))) float f32x4;

__device__ __forceinline__ unsigned short f2bf(float f) {
  unsigned u = __float_as_uint(f);
  u += 0x7FFFu + ((u >> 16) & 1u);   // RNE
  return (unsigned short)(u >> 16);
}
__device__ __forceinline__ float bf2f(unsigned short s) {
  return __uint_as_float(((unsigned)s) << 16);
}

// async global->LDS, 16B per lane; dst must be wave-uniform base (HW adds lane*16)
#define GLOAD_LDS16(src, dst)                                                   \
  __builtin_amdgcn_global_load_lds(                                             \
      (const void __attribute__((address_space(1)))*)(src),                     \
      (void __attribute__((address_space(3)))*)(dst), 16, 0, 0)

// ---------------- fp32 -> bf16 convert (vectorized x4) ----------------
__global__ void cvt_f32_bf16(const float* __restrict__ in,
                             unsigned short* __restrict__ out, int n4) {
  int i = blockIdx.x * blockDim.x + threadIdx.x;
  if (i < n4) {
    float4 v = ((const float4*)in)[i];
    ushort4 o;
    o.x = f2bf(v.x); o.y = f2bf(v.y); o.z = f2bf(v.z); o.w = f2bf(v.w);
    ((ushort4*)out)[i] = o;
  }
}

// fused convert of the three (DD x DD) qkv weights into one contiguous buffer
__global__ void cvt_w3(const float* __restrict__ a, const float* __restrict__ b,
                       const float* __restrict__ c, unsigned short* __restrict__ out) {
  int i = blockIdx.x * blockDim.x + threadIdx.x;  // < 3 << 20
  int sel = i >> 20, r = i & 0xFFFFF;             // DD*DD/4 == 1<<20
  const float* src = sel == 0 ? a : (sel == 1 ? b : c);
  float4 v = ((const float4*)src)[r];
  ushort4 o;
  o.x = f2bf(v.x); o.y = f2bf(v.y); o.z = f2bf(v.z); o.w = f2bf(v.w);
  ((ushort4*)out)[i] = o;
}

__global__ void concat3(const float* __restrict__ a, const float* __restrict__ b,
                        const float* __restrict__ c, float* __restrict__ out) {
  int i = blockIdx.x * blockDim.x + threadIdx.x;
  if (i < DD) { out[i] = a[i]; out[DD + i] = b[i]; out[2 * DD + i] = c[i]; }
}

// ---------------- bf16 GEMM: C[M][N] = A[M][K] @ W[N][K]^T + bias[N] ----------------
// m97-style: 128x128 tile, BK=32, 4 waves in 2x2 quadrants, 16x16x32 bf16 MFMA.
template <bool OUT_BF16>
__global__ __launch_bounds__(256, 2) void gemm_bt(
    const __bf16* __restrict__ A, const __bf16* __restrict__ W,
    const float* __restrict__ bias, void* __restrict__ Cout,
    int M, int N, int K) {
  __shared__ __bf16 lA[128 * 32];  // 8 KB, row-major [128][32], no pad (global_load_lds)
  __shared__ __bf16 lB[128 * 32];
  const int t = threadIdx.x;
  const int lane = t & 63, wave = t >> 6;
  const int quad = lane >> 4, l16 = lane & 15;
  const int m0 = blockIdx.y * 128, n0 = blockIdx.x * 128;
  const int wm = (wave & 1) * 64, wn = (wave >> 1) * 64;

  f32x4 acc[4][4] = {};

  for (int k0 = 0; k0 < K; k0 += 32) {
#pragma unroll
    for (int c = 0; c < 2; ++c) {
      int lin = c * 256 + t;          // 16B-chunk id, 4 chunks per 32-col row
      int row = lin >> 2;
      int col = (lin & 3) * 8;
      const __bf16* srcA = A + (size_t)(m0 + row) * K + k0 + col;
      const __bf16* srcB = W + (size_t)(n0 + row) * K + k0 + col;
      GLOAD_LDS16(srcA, &lA[(c * 256 + wave * 64) * 8]);
      GLOAD_LDS16(srcB, &lB[(c * 256 + wave * 64) * 8]);
    }
    __syncthreads();  // drains vmcnt -> LDS tile ready
    bf16x8 af[4], bfr[4];
#pragma unroll
    for (int mt = 0; mt < 4; ++mt)
      af[mt] = *(const bf16x8*)&lA[(wm + mt * 16 + l16) * 32 + quad * 8];
#pragma unroll
    for (int nt = 0; nt < 4; ++nt)
      bfr[nt] = *(const bf16x8*)&lB[(wn + nt * 16 + l16) * 32 + quad * 8];
#pragma unroll
    for (int mt = 0; mt < 4; ++mt)
#pragma unroll
      for (int nt = 0; nt < 4; ++nt)
        acc[mt][nt] = __builtin_amdgcn_mfma_f32_16x16x32_bf16(af[mt], bfr[nt],
                                                              acc[mt][nt], 0, 0, 0);
    __syncthreads();  // protect LDS before next stage
  }

  // epilogue: C/D layout col=lane&15, row=quad*4+reg  [m89/m91 verified]
#pragma unroll
  for (int mt = 0; mt < 4; ++mt) {
#pragma unroll
    for (int nt = 0; nt < 4; ++nt) {
      int col = n0 + wn + nt * 16 + l16;
      float bv = bias[col];
#pragma unroll
      for (int r = 0; r < 4; ++r) {
        int row = m0 + wm + mt * 16 + quad * 4 + r;
        float v = acc[mt][nt][r] + bv;
        if constexpr (OUT_BF16)
          ((unsigned short*)Cout)[(size_t)row * N + col] = f2bf(v);
        else
          ((float*)Cout)[(size_t)row * N + col] = v;
      }
    }
  }
}

// ---------------- QK^T upper-triangle exp row-sums + diagonal ----------------
// Work-balanced: block (p, bh) handles i-tiles p and 31-p (trip counts sum to 17
// j-tiles exactly, for every p). Grid (16, BHH) = 512 uniform blocks = 2/CU.
// denom[i] = i + sum_{j>=i} exp(s_ij*scale); diag[i] = exp(s_ii*scale).
__global__ __launch_bounds__(256, 2) void qk_rowsum(
    const __bf16* __restrict__ q0, const __bf16* __restrict__ k0,
    float* __restrict__ denom, float* __restrict__ diag) {
  // LDS layout [ks=4][row=128][32] so fragment reads have 64B row stride
  __shared__ __bf16 lK[4 * 128 * 32];  // 32 KB
  const int t = threadIdx.x;
  const int lane = t & 63, wave = t >> 6;
  const int quad = lane >> 4, l16 = lane & 15;
  const int bh = blockIdx.y;
  const int b = bh >> 4, h = bh & 15;
  const float scale = 0.02209708691207961f;  // 1/sqrt(2048)

#pragma unroll
  for (int sub = 0; sub < 2; ++sub) {
    const int tile = (sub == 0) ? (int)blockIdx.x : 31 - (int)blockIdx.x;
    const int i0 = tile * 64;
    const int rowg = i0 + wave * 16;  // wave's rows: rowg + (0..15)

    // Q fragments for this wave's 16 rows, all 4 k-steps (K=HDIM=128), in regs
    bf16x8 af[4];
    const __bf16* qbase = q0 + (size_t)(b * SS + rowg + l16) * QD + h * HDIM;
#pragma unroll
    for (int ks = 0; ks < 4; ++ks)
      af[ks] = *(const bf16x8*)(qbase + ks * 32 + quad * 8);

    float rowsum[4] = {0.f, 0.f, 0.f, 0.f};
    float diagv[4] = {0.f, 0.f, 0.f, 0.f};

    for (int j0 = i0 & ~127; j0 < SS; j0 += 128) {
      // stage K-tile [128 rows][128 k] into [ks][row][32] layout
#pragma unroll
      for (int c = 0; c < 8; ++c) {
        int L = c * 256 + t;        // 16B-chunk id, 2048 total
        int ks = L >> 9;            // 512 chunks per ks-slice
        int rem = L & 511;
        int row = rem >> 2;
        int c4 = rem & 3;
        const __bf16* src =
            k0 + (size_t)(b * SS + j0 + row) * QD + h * HDIM + ks * 32 + c4 * 8;
        GLOAD_LDS16(src, &lK[(c * 256 + wave * 64) * 8]);
      }
      __syncthreads();
#pragma unroll
      for (int nt = 0; nt < 8; ++nt) {
        f32x4 acc = {0.f, 0.f, 0.f, 0.f};
#pragma unroll
        for (int ks = 0; ks < 4; ++ks) {
          bf16x8 bfr =
              *(const bf16x8*)&lK[ks * 4096 + (nt * 16 + l16) * 32 + quad * 8];
          acc = __builtin_amdgcn_mfma_f32_16x16x32_bf16(af[ks], bfr, acc, 0, 0, 0);
        }
        int colg = j0 + nt * 16 + l16;
#pragma unroll
        for (int r = 0; r < 4; ++r) {
          int rg = rowg + quad * 4 + r;
          if (colg >= rg) {
            float e = __expf(acc[r] * scale);
            rowsum[r] += e;
            if (colg == rg) diagv[r] = e;
          }
        }
      }
      __syncthreads();
    }

    // reduce over the 16 column-lanes (lanes quad*16 .. quad*16+15)
#pragma unroll
    for (int r = 0; r < 4; ++r) {
      float s = rowsum[r], d = diagv[r];
#pragma unroll
      for (int off = 1; off < 16; off <<= 1) {
        s += __shfl_xor(s, off, 64);
        d += __shfl_xor(d, off, 64);
      }
      if (l16 == 0) {
        int rg = rowg + quad * 4 + r;
        denom[bh * SS + rg] = (float)rg + s;
        diag[bh * SS + rg] = d;
      }
    }
    // safe to restage lK immediately: j-loop ended with __syncthreads and no
    // lK reads occur after it
  }
}

// ---------------- V prefix-scan, two-pass, 16B/lane ----------------
// grid = BHH*NCHUNK blocks, 256 threads: thread = (rs = 8-row subslice, dg = 8-dim group)
__global__ void scan_pass1(const __bf16* __restrict__ v0,
                           float* __restrict__ csum) {
  int blk = blockIdx.x;
  int bh = blk >> 4, c = blk & 15;
  int b = bh >> 4, h = bh & 15;
  int t = threadIdx.x;
  int rs = t >> 4, dg = t & 15;
  const unsigned short* base = (const unsigned short*)v0 +
      (size_t)(b * SS + c * 128 + rs * 8) * QD + h * HDIM + dg * 8;
  float s[8] = {0.f, 0.f, 0.f, 0.f, 0.f, 0.f, 0.f, 0.f};
#pragma unroll
  for (int i = 0; i < 8; ++i) {
    uint4 u = *(const uint4*)(base + (size_t)i * QD);
    const unsigned short* us = (const unsigned short*)&u;
#pragma unroll
    for (int j = 0; j < 8; ++j) s[j] += bf2f(us[j]);
  }
  __shared__ float red[16 * 128];
#pragma unroll
  for (int j = 0; j < 8; ++j) red[rs * 128 + dg * 8 + j] = s[j];
  __syncthreads();
  for (int st = 8; st >= 1; st >>= 1) {
    if (rs < st) {
#pragma unroll
      for (int j = 0; j < 8; ++j)
        red[rs * 128 + dg * 8 + j] += red[(rs + st) * 128 + dg * 8 + j];
    }
    __syncthreads();
  }
  if (rs == 0) {
#pragma unroll
    for (int j = 0; j < 8; ++j)
      csum[(size_t)blk * 128 + dg * 8 + j] = red[dg * 8 + j];
  }
}

// pass2: within-chunk scan, write ctx = (prefix_excl + diag*v)/denom (bf16)
__global__ void scan_pass2(const __bf16* __restrict__ v0,
                           const float* __restrict__ csum,
                           const float* __restrict__ denom,
                           const float* __restrict__ diag,
                           unsigned short* __restrict__ ctx) {
  int blk = blockIdx.x;
  int bh = blk >> 4, c = blk & 15;
  int b = bh >> 4, h = bh & 15;
  int t = threadIdx.x;
  int rs = t >> 4, dg = t & 15;
  const unsigned short* vbase = (const unsigned short*)v0 +
      (size_t)(b * SS + c * 128 + rs * 8) * QD + h * HDIM + dg * 8;
  float vrow[8][8];
  float ls[8] = {0.f, 0.f, 0.f, 0.f, 0.f, 0.f, 0.f, 0.f};
#pragma unroll
  for (int i = 0; i < 8; ++i) {
    uint4 u = *(const uint4*)(vbase + (size_t)i * QD);
    const unsigned short* us = (const unsigned short*)&u;
#pragma unroll
    for (int j = 0; j < 8; ++j) {
      vrow[i][j] = bf2f(us[j]);
      ls[j] += vrow[i][j];
    }
  }
  __shared__ float red[16 * 128];
#pragma unroll
  for (int j = 0; j < 8; ++j) red[rs * 128 + dg * 8 + j] = ls[j];
  __syncthreads();

  float pre[8] = {0.f, 0.f, 0.f, 0.f, 0.f, 0.f, 0.f, 0.f};
  // exclusive prefix from previous chunks
  for (int cc = 0; cc < c; ++cc) {
    const float* cp = csum + (size_t)(bh * 16 + cc) * 128 + dg * 8;
#pragma unroll
    for (int j = 0; j < 8; ++j) pre[j] += cp[j];
  }
  // exclusive prefix from previous subslices in this chunk
  for (int ss2 = 0; ss2 < rs; ++ss2) {
#pragma unroll
    for (int j = 0; j < 8; ++j) pre[j] += red[ss2 * 128 + dg * 8 + j];
  }

  int row0 = c * 128 + rs * 8;
  unsigned short* obase =
      ctx + (size_t)(b * SS + row0) * DD + h * HDIM + dg * 8;
  const float* dn = denom + bh * SS + row0;
  const float* dgp = diag + bh * SS + row0;
#pragma unroll
  for (int i = 0; i < 8; ++i) {
    float inv = 1.0f / dn[i];
    float dv = dgp[i];
    unsigned short o[8];
#pragma unroll
    for (int j = 0; j < 8; ++j) {
      float val = (pre[j] + dv * vrow[i][j]) * inv;
      o[j] = f2bf(val);
      pre[j] += vrow[i][j];
    }
    *(uint4*)(obase + (size_t)i * DD) = *(const uint4*)o;
  }
}

extern "C" void kernel_launch(void* const* d_in, const int* in_sizes, int n_in,
                              void* d_out, int out_size, void* d_ws, size_t ws_size,
                              hipStream_t stream) {
  (void)in_sizes; (void)n_in; (void)out_size; (void)ws_size;
  const float* x    = (const float*)d_in[0];
  const float* wq_w = (const float*)d_in[1];
  const float* wq_b = (const float*)d_in[2];
  const float* wk_w = (const float*)d_in[3];
  const float* wk_b = (const float*)d_in[4];
  const float* wv_w = (const float*)d_in[5];
  const float* wv_b = (const float*)d_in[6];
  const float* wo_w = (const float*)d_in[7];
  const float* wo_b = (const float*)d_in[8];

  char* ws = (char*)d_ws;
  size_t off = 0;
  auto alloc = [&](size_t bytes) {
    char* p = ws + off;
    off += (bytes + 255) & ~(size_t)255;
    return p;
  };
  unsigned short* xb    = (unsigned short*)alloc((size_t)MTOK * DD * 2);   // 16 MB
  unsigned short* wqkvb = (unsigned short*)alloc((size_t)3 * DD * DD * 2); // 24 MB
  unsigned short* wob   = (unsigned short*)alloc((size_t)DD * DD * 2);     // 8 MB
  unsigned short* qkv   = (unsigned short*)alloc((size_t)MTOK * QD * 2);   // 48 MB
  unsigned short* ctx   = (unsigned short*)alloc((size_t)MTOK * DD * 2);   // 16 MB
  float* biasqkv = (float*)alloc((size_t)3 * DD * 4);
  float* denom   = (float*)alloc((size_t)BHH * SS * 4);
  float* diag    = (float*)alloc((size_t)BHH * SS * 4);
  float* csum    = (float*)alloc((size_t)BHH * NCHUNK * 128 * 4);

  // 1) converts
  {
    int n4 = MTOK * DD / 4;
    cvt_f32_bf16<<<n4 / 256, 256, 0, stream>>>(x, xb, n4);
    cvt_w3<<<(3 << 20) / 256, 256, 0, stream>>>(wq_w, wk_w, wv_w, wqkvb);
    int w4 = DD * DD / 4;
    cvt_f32_bf16<<<w4 / 256, 256, 0, stream>>>(wo_w, wob, w4);
    concat3<<<(DD + 255) / 256, 256, 0, stream>>>(wq_b, wk_b, wv_b, biasqkv);
  }

  // 2) fused QKV GEMM: [4096,2048] x [6144,2048]^T -> qkv bf16 [4096][6144]
  gemm_bt<true><<<dim3(QD / 128, MTOK / 128), 256, 0, stream>>>(
      (const __bf16*)xb, (const __bf16*)wqkvb, biasqkv, qkv, MTOK, QD, DD);

  // 3) denominators + diagonal exps (work-balanced paired i-tiles)
  qk_rowsum<<<dim3(16, BHH), 256, 0, stream>>>(
      (const __bf16*)qkv,                 // q at col 0
      (const __bf16*)qkv + DD,            // k at col 2048
      denom, diag);

  // 4) V scan -> ctx
  scan_pass1<<<BHH * NCHUNK, 256, 0, stream>>>((const __bf16*)qkv + 2 * DD, csum);
  scan_pass2<<<BHH * NCHUNK, 256, 0, stream>>>((const __bf16*)qkv + 2 * DD, csum,
                                               denom, diag, ctx);

  // 5) output projection: [4096,2048] x [2048,2048]^T -> d_out fp32
  gemm_bt<false><<<dim3(DD / 128, MTOK / 128), 256, 0, stream>>>(
      (const __bf16*)ctx, (const __bf16*)wob, wo_b, d_out, MTOK, DD, DD);
}

// Round 3
// 394.366 us; speedup vs baseline: 1.1281x; 1.0346x over previous
//
#include <hip/hip_runtime.h>

// Problem constants
#define BB 2
#define SS 2048
#define DD 2048
#define HH 16
#define HDIM 128
#define MTOK (BB*SS)     // 4096 token rows
#define BHH (BB*HH)      // 32 (b,h) pairs
#define NCHUNK 16        // scan chunks per (b,h): 2048/128
#define QKN (2*DD)       // fp8 qk row stride (q cols 0..2047, k cols 2048..4095)

typedef __attribute__((ext_vector_type(8))) __bf16 bf16x8;
typedef __attribute__((ext_vector_type(4))) float f32x4;

__device__ __forceinline__ unsigned short f2bf(float f) {
  unsigned u = __float_as_uint(f);
  u += 0x7FFFu + ((u >> 16) & 1u);   // RNE
  return (unsigned short)(u >> 16);
}
__device__ __forceinline__ float bf2f(unsigned short s) {
  return __uint_as_float(((unsigned)s) << 16);
}
__device__ __forceinline__ unsigned char f2e4m3(float f) {
  // HW convert, OCP e4m3fn on gfx950, saturating
  int pk = __builtin_amdgcn_cvt_pk_fp8_f32(f, f, 0, false);
  return (unsigned char)(pk & 0xFF);
}

// async global->LDS, 16B per lane; dst must be wave-uniform base (HW adds lane*16)
#define GLOAD_LDS16(src, dst)                                                   \
  __builtin_amdgcn_global_load_lds(                                             \
      (const void __attribute__((address_space(1)))*)(src),                     \
      (void __attribute__((address_space(3)))*)(dst), 16, 0, 0)

// ---------------- converts ----------------
// x -> bf16 (for V gemm) and fp8 (for QK gemm) in one pass
__global__ void cvt_x_dual(const float* __restrict__ in,
                           unsigned short* __restrict__ outb,
                           unsigned int* __restrict__ out8, int n4) {
  int i = blockIdx.x * blockDim.x + threadIdx.x;
  if (i < n4) {
    float4 v = ((const float4*)in)[i];
    ushort4 o;
    o.x = f2bf(v.x); o.y = f2bf(v.y); o.z = f2bf(v.z); o.w = f2bf(v.w);
    ((ushort4*)outb)[i] = o;
    int p0 = __builtin_amdgcn_cvt_pk_fp8_f32(v.x, v.y, 0, false);
    int p1 = __builtin_amdgcn_cvt_pk_fp8_f32(v.z, v.w, 0, false);
    out8[i] = (unsigned)(p0 & 0xFFFF) | ((unsigned)(p1 & 0xFFFF) << 16);
  }
}

// wq,wk -> fp8 contiguous [2*DD][DD]
__global__ void cvt_wqk8(const float* __restrict__ a, const float* __restrict__ b,
                         unsigned int* __restrict__ out) {
  int i = blockIdx.x * blockDim.x + threadIdx.x;  // < 2<<20
  int sel = i >> 20, r = i & 0xFFFFF;             // DD*DD/4 == 1<<20
  const float* src = sel == 0 ? a : b;
  float4 v = ((const float4*)src)[r];
  int p0 = __builtin_amdgcn_cvt_pk_fp8_f32(v.x, v.y, 0, false);
  int p1 = __builtin_amdgcn_cvt_pk_fp8_f32(v.z, v.w, 0, false);
  out[i] = (unsigned)(p0 & 0xFFFF) | ((unsigned)(p1 & 0xFFFF) << 16);
}

// wv,wo -> bf16, contiguous dest (wv at 0, wo at DD*DD)
__global__ void cvt_w2bf(const float* __restrict__ a, const float* __restrict__ b,
                         unsigned short* __restrict__ out) {
  int i = blockIdx.x * blockDim.x + threadIdx.x;  // < 2<<20
  int sel = i >> 20, r = i & 0xFFFFF;
  const float* src = sel == 0 ? a : b;
  float4 v = ((const float4*)src)[r];
  ushort4 o;
  o.x = f2bf(v.x); o.y = f2bf(v.y); o.z = f2bf(v.z); o.w = f2bf(v.w);
  ((ushort4*)out)[i] = o;
}

__global__ void concat2(const float* __restrict__ a, const float* __restrict__ b,
                        float* __restrict__ out) {
  int i = blockIdx.x * blockDim.x + threadIdx.x;
  if (i < DD) { out[i] = a[i]; out[DD + i] = b[i]; }
}

// ---------------- bf16 GEMM: C[M][N] = A[M][K] @ W[N][K]^T + bias[N] ----------------
// 128x128 tile, BK=32, 4 waves 2x2, 16x16x32 bf16 MFMA.
// LDS bank-conflict fix: source-swizzle 16B chunks, chunk_pos = c4 ^ (row&3).
template <bool OUT_BF16>
__global__ __launch_bounds__(256, 2) void gemm_bt(
    const __bf16* __restrict__ A, const __bf16* __restrict__ W,
    const float* __restrict__ bias, void* __restrict__ Cout,
    int M, int N, int K) {
  __shared__ __bf16 lA[128 * 32];  // 8 KB
  __shared__ __bf16 lB[128 * 32];
  const int t = threadIdx.x;
  const int lane = t & 63, wave = t >> 6;
  const int quad = lane >> 4, l16 = lane & 15;
  const int m0 = blockIdx.y * 128, n0 = blockIdx.x * 128;
  const int wm = (wave & 1) * 64, wn = (wave >> 1) * 64;

  f32x4 acc[4][4] = {};

  for (int k0 = 0; k0 < K; k0 += 32) {
#pragma unroll
    for (int c = 0; c < 2; ++c) {
      int lin = c * 256 + t;          // 16B-chunk id
      int row = lin >> 2;
      int c4 = (lin & 3) ^ (row & 3); // source swizzle (self-inverse)
      const __bf16* srcA = A + (size_t)(m0 + row) * K + k0 + c4 * 8;
      const __bf16* srcB = W + (size_t)(n0 + row) * K + k0 + c4 * 8;
      GLOAD_LDS16(srcA, &lA[(c * 256 + wave * 64) * 8]);
      GLOAD_LDS16(srcB, &lB[(c * 256 + wave * 64) * 8]);
    }
    __syncthreads();
    bf16x8 af[4], bfr[4];
#pragma unroll
    for (int mt = 0; mt < 4; ++mt) {
      int row = wm + mt * 16 + l16;
      af[mt] = *(const bf16x8*)&lA[row * 32 + (quad ^ (row & 3)) * 8];
    }
#pragma unroll
    for (int nt = 0; nt < 4; ++nt) {
      int row = wn + nt * 16 + l16;
      bfr[nt] = *(const bf16x8*)&lB[row * 32 + (quad ^ (row & 3)) * 8];
    }
#pragma unroll
    for (int mt = 0; mt < 4; ++mt)
#pragma unroll
      for (int nt = 0; nt < 4; ++nt)
        acc[mt][nt] = __builtin_amdgcn_mfma_f32_16x16x32_bf16(af[mt], bfr[nt],
                                                              acc[mt][nt], 0, 0, 0);
    __syncthreads();
  }

  // epilogue: C/D layout col=lane&15, row=quad*4+reg  [m89/m91 verified]
#pragma unroll
  for (int mt = 0; mt < 4; ++mt) {
#pragma unroll
    for (int nt = 0; nt < 4; ++nt) {
      int col = n0 + wn + nt * 16 + l16;
      float bv = bias[col];
#pragma unroll
      for (int r = 0; r < 4; ++r) {
        int row = m0 + wm + mt * 16 + quad * 4 + r;
        float v = acc[mt][nt][r] + bv;
        if constexpr (OUT_BF16)
          ((unsigned short*)Cout)[(size_t)row * N + col] = f2bf(v);
        else
          ((float*)Cout)[(size_t)row * N + col] = v;
      }
    }
  }
}

// ---------------- fp8 GEMM: C8[M][N] = e4m3( A8[M][K] @ W8[N][K]^T + bias ) ----------------
// 128x128 tile, BK=64, 16x16x32 fp8 MFMA, source-swizzled staging.
__global__ __launch_bounds__(256, 2) void gemm_qk_fp8(
    const unsigned char* __restrict__ A8, const unsigned char* __restrict__ W8,
    const float* __restrict__ bias, unsigned char* __restrict__ Cout,
    int M, int N, int K) {
  __shared__ unsigned char lA[128 * 64];  // 8 KB
  __shared__ unsigned char lB[128 * 64];
  const int t = threadIdx.x;
  const int lane = t & 63, wave = t >> 6;
  const int quad = lane >> 4, l16 = lane & 15;
  const int m0 = blockIdx.y * 128, n0 = blockIdx.x * 128;
  const int wm = (wave & 1) * 64, wn = (wave >> 1) * 64;

  f32x4 acc[4][4] = {};

  for (int k0 = 0; k0 < K; k0 += 64) {
#pragma unroll
    for (int c = 0; c < 2; ++c) {
      int lin = c * 256 + t;          // 16B-chunk id, 4 per 64B row
      int row = lin >> 2;
      int c4 = (lin & 3) ^ (row & 3); // source swizzle
      const unsigned char* srcA = A8 + (size_t)(m0 + row) * K + k0 + c4 * 16;
      const unsigned char* srcB = W8 + (size_t)(n0 + row) * K + k0 + c4 * 16;
      GLOAD_LDS16(srcA, &lA[(c * 256 + wave * 64) * 16]);
      GLOAD_LDS16(srcB, &lB[(c * 256 + wave * 64) * 16]);
    }
    __syncthreads();
    long long af[2][4], bfr[2][4];
#pragma unroll
    for (int ks = 0; ks < 2; ++ks) {
#pragma unroll
      for (int mt = 0; mt < 4; ++mt) {
        int row = wm + mt * 16 + l16;
        int chunk = (ks * 2 + (quad >> 1)) ^ (row & 3);
        af[ks][mt] = *(const long long*)&lA[row * 64 + chunk * 16 + (quad & 1) * 8];
      }
#pragma unroll
      for (int nt = 0; nt < 4; ++nt) {
        int row = wn + nt * 16 + l16;
        int chunk = (ks * 2 + (quad >> 1)) ^ (row & 3);
        bfr[ks][nt] = *(const long long*)&lB[row * 64 + chunk * 16 + (quad & 1) * 8];
      }
    }
#pragma unroll
    for (int mt = 0; mt < 4; ++mt)
#pragma unroll
      for (int nt = 0; nt < 4; ++nt)
#pragma unroll
        for (int ks = 0; ks < 2; ++ks)
          acc[mt][nt] = __builtin_amdgcn_mfma_f32_16x16x32_fp8_fp8(
              af[ks][mt], bfr[ks][nt], acc[mt][nt], 0, 0, 0);
    __syncthreads();
  }

#pragma unroll
  for (int mt = 0; mt < 4; ++mt) {
#pragma unroll
    for (int nt = 0; nt < 4; ++nt) {
      int col = n0 + wn + nt * 16 + l16;
      float bv = bias[col];
#pragma unroll
      for (int r = 0; r < 4; ++r) {
        int row = m0 + wm + mt * 16 + quad * 4 + r;
        Cout[(size_t)row * N + col] = f2e4m3(acc[mt][nt][r] + bv);
      }
    }
  }
}

// ---------------- QK^T upper-triangle exp row-sums + diagonal (fp8) ----------------
// Work-balanced: block (p, bh) handles i-tiles p and 31-p (trips sum to 17).
// denom[i] = i + sum_{j>=i} exp(s_ij*scale); diag[i] = exp(s_ii*scale).
__global__ __launch_bounds__(256, 2) void qk_rowsum8(
    const unsigned char* __restrict__ q8, const unsigned char* __restrict__ k8,
    float* __restrict__ denom, float* __restrict__ diag) {
  // LDS layout [ks=4][row=128][32 B]
  __shared__ unsigned char lK[4 * 128 * 32];  // 16 KB
  const int t = threadIdx.x;
  const int lane = t & 63, wave = t >> 6;
  const int quad = lane >> 4, l16 = lane & 15;
  const int bh = blockIdx.y;
  const int b = bh >> 4, h = bh & 15;
  const float scale = 0.02209708691207961f;  // 1/sqrt(2048)

#pragma unroll
  for (int sub = 0; sub < 2; ++sub) {
    const int tile = (sub == 0) ? (int)blockIdx.x : 31 - (int)blockIdx.x;
    const int i0 = tile * 64;
    const int rowg = i0 + wave * 16;

    long long af[4];
    const unsigned char* qbase =
        q8 + (size_t)(b * SS + rowg + l16) * QKN + h * HDIM;
#pragma unroll
    for (int ks = 0; ks < 4; ++ks)
      af[ks] = *(const long long*)(qbase + ks * 32 + quad * 8);

    float rowsum[4] = {0.f, 0.f, 0.f, 0.f};
    float diagv[4] = {0.f, 0.f, 0.f, 0.f};

    for (int j0 = i0 & ~127; j0 < SS; j0 += 128) {
      // stage K-tile [128 rows][128 B] into [ks][row][32 B]
#pragma unroll
      for (int c = 0; c < 4; ++c) {
        int L = c * 256 + t;        // 16B-chunk id, 1024 total
        int ks = L >> 8;            // 256 chunks per ks-slice
        int rem = L & 255;
        int row = rem >> 1;
        int c2 = rem & 1;
        const unsigned char* src =
            k8 + (size_t)(b * SS + j0 + row) * QKN + h * HDIM + ks * 32 + c2 * 16;
        GLOAD_LDS16(src, &lK[(c * 256 + wave * 64) * 16]);
      }
      __syncthreads();
#pragma unroll
      for (int nt = 0; nt < 8; ++nt) {
        f32x4 acc = {0.f, 0.f, 0.f, 0.f};
#pragma unroll
        for (int ks = 0; ks < 4; ++ks) {
          long long bfr =
              *(const long long*)&lK[ks * 4096 + (nt * 16 + l16) * 32 + quad * 8];
          acc = __builtin_amdgcn_mfma_f32_16x16x32_fp8_fp8(af[ks], bfr, acc, 0, 0, 0);
        }
        int colg = j0 + nt * 16 + l16;
#pragma unroll
        for (int r = 0; r < 4; ++r) {
          int rg = rowg + quad * 4 + r;
          if (colg >= rg) {
            float e = __expf(acc[r] * scale);
            rowsum[r] += e;
            if (colg == rg) diagv[r] = e;
          }
        }
      }
      __syncthreads();
    }

#pragma unroll
    for (int r = 0; r < 4; ++r) {
      float s = rowsum[r], d = diagv[r];
#pragma unroll
      for (int off = 1; off < 16; off <<= 1) {
        s += __shfl_xor(s, off, 64);
        d += __shfl_xor(d, off, 64);
      }
      if (l16 == 0) {
        int rg = rowg + quad * 4 + r;
        denom[bh * SS + rg] = (float)rg + s;
        diag[bh * SS + rg] = d;
      }
    }
  }
}

// ---------------- V prefix-scan, two-pass, 16B/lane ----------------
// v is a dedicated [MTOK][DD] bf16 buffer now.
__global__ void scan_pass1(const __bf16* __restrict__ v0,
                           float* __restrict__ csum) {
  int blk = blockIdx.x;
  int bh = blk >> 4, c = blk & 15;
  int b = bh >> 4, h = bh & 15;
  int t = threadIdx.x;
  int rs = t >> 4, dg = t & 15;
  const unsigned short* base = (const unsigned short*)v0 +
      (size_t)(b * SS + c * 128 + rs * 8) * DD + h * HDIM + dg * 8;
  float s[8] = {0.f, 0.f, 0.f, 0.f, 0.f, 0.f, 0.f, 0.f};
#pragma unroll
  for (int i = 0; i < 8; ++i) {
    uint4 u = *(const uint4*)(base + (size_t)i * DD);
    const unsigned short* us = (const unsigned short*)&u;
#pragma unroll
    for (int j = 0; j < 8; ++j) s[j] += bf2f(us[j]);
  }
  __shared__ float red[16 * 128];
#pragma unroll
  for (int j = 0; j < 8; ++j) red[rs * 128 + dg * 8 + j] = s[j];
  __syncthreads();
  for (int st = 8; st >= 1; st >>= 1) {
    if (rs < st) {
#pragma unroll
      for (int j = 0; j < 8; ++j)
        red[rs * 128 + dg * 8 + j] += red[(rs + st) * 128 + dg * 8 + j];
    }
    __syncthreads();
  }
  if (rs == 0) {
#pragma unroll
    for (int j = 0; j < 8; ++j)
      csum[(size_t)blk * 128 + dg * 8 + j] = red[dg * 8 + j];
  }
}

__global__ void scan_pass2(const __bf16* __restrict__ v0,
                           const float* __restrict__ csum,
                           const float* __restrict__ denom,
                           const float* __restrict__ diag,
                           unsigned short* __restrict__ ctx) {
  int blk = blockIdx.x;
  int bh = blk >> 4, c = blk & 15;
  int b = bh >> 4, h = bh & 15;
  int t = threadIdx.x;
  int rs = t >> 4, dg = t & 15;
  const unsigned short* vbase = (const unsigned short*)v0 +
      (size_t)(b * SS + c * 128 + rs * 8) * DD + h * HDIM + dg * 8;
  float vrow[8][8];
  float ls[8] = {0.f, 0.f, 0.f, 0.f, 0.f, 0.f, 0.f, 0.f};
#pragma unroll
  for (int i = 0; i < 8; ++i) {
    uint4 u = *(const uint4*)(vbase + (size_t)i * DD);
    const unsigned short* us = (const unsigned short*)&u;
#pragma unroll
    for (int j = 0; j < 8; ++j) {
      vrow[i][j] = bf2f(us[j]);
      ls[j] += vrow[i][j];
    }
  }
  __shared__ float red[16 * 128];
#pragma unroll
  for (int j = 0; j < 8; ++j) red[rs * 128 + dg * 8 + j] = ls[j];
  __syncthreads();

  float pre[8] = {0.f, 0.f, 0.f, 0.f, 0.f, 0.f, 0.f, 0.f};
  for (int cc = 0; cc < c; ++cc) {
    const float* cp = csum + (size_t)(bh * 16 + cc) * 128 + dg * 8;
#pragma unroll
    for (int j = 0; j < 8; ++j) pre[j] += cp[j];
  }
  for (int ss2 = 0; ss2 < rs; ++ss2) {
#pragma unroll
    for (int j = 0; j < 8; ++j) pre[j] += red[ss2 * 128 + dg * 8 + j];
  }

  int row0 = c * 128 + rs * 8;
  unsigned short* obase =
      ctx + (size_t)(b * SS + row0) * DD + h * HDIM + dg * 8;
  const float* dn = denom + bh * SS + row0;
  const float* dgp = diag + bh * SS + row0;
#pragma unroll
  for (int i = 0; i < 8; ++i) {
    float inv = 1.0f / dn[i];
    float dv = dgp[i];
    unsigned short o[8];
#pragma unroll
    for (int j = 0; j < 8; ++j) {
      float val = (pre[j] + dv * vrow[i][j]) * inv;
      o[j] = f2bf(val);
      pre[j] += vrow[i][j];
    }
    *(uint4*)(obase + (size_t)i * DD) = *(const uint4*)o;
  }
}

extern "C" void kernel_launch(void* const* d_in, const int* in_sizes, int n_in,
                              void* d_out, int out_size, void* d_ws, size_t ws_size,
                              hipStream_t stream) {
  (void)in_sizes; (void)n_in; (void)out_size; (void)ws_size;
  const float* x    = (const float*)d_in[0];
  const float* wq_w = (const float*)d_in[1];
  const float* wq_b = (const float*)d_in[2];
  const float* wk_w = (const float*)d_in[3];
  const float* wk_b = (const float*)d_in[4];
  const float* wv_w = (const float*)d_in[5];
  const float* wv_b = (const float*)d_in[6];
  const float* wo_w = (const float*)d_in[7];
  const float* wo_b = (const float*)d_in[8];

  char* ws = (char*)d_ws;
  size_t off = 0;
  auto alloc = [&](size_t bytes) {
    char* p = ws + off;
    off += (bytes + 255) & ~(size_t)255;
    return p;
  };
  unsigned short* xb   = (unsigned short*)alloc((size_t)MTOK * DD * 2);    // 16 MB
  unsigned char*  x8   = (unsigned char*)alloc((size_t)MTOK * DD);         // 8 MB
  unsigned char*  wqk8 = (unsigned char*)alloc((size_t)2 * DD * DD);       // 8 MB
  unsigned short* wvo  = (unsigned short*)alloc((size_t)2 * DD * DD * 2);  // 16 MB (wv | wo)
  unsigned char*  qk8  = (unsigned char*)alloc((size_t)MTOK * QKN);        // 16 MB
  unsigned short* v    = (unsigned short*)alloc((size_t)MTOK * DD * 2);    // 16 MB
  unsigned short* ctx  = (unsigned short*)alloc((size_t)MTOK * DD * 2);    // 16 MB
  float* biasqk = (float*)alloc((size_t)2 * DD * 4);
  float* denom  = (float*)alloc((size_t)BHH * SS * 4);
  float* diag   = (float*)alloc((size_t)BHH * SS * 4);
  float* csum   = (float*)alloc((size_t)BHH * NCHUNK * 128 * 4);

  // 1) converts
  {
    int n4 = MTOK * DD / 4;
    cvt_x_dual<<<n4 / 256, 256, 0, stream>>>(x, xb, (unsigned int*)x8, n4);
    cvt_wqk8<<<(2 << 20) / 256, 256, 0, stream>>>(wq_w, wk_w, (unsigned int*)wqk8);
    cvt_w2bf<<<(2 << 20) / 256, 256, 0, stream>>>(wv_w, wo_w, wvo);
    concat2<<<(DD + 255) / 256, 256, 0, stream>>>(wq_b, wk_b, biasqk);
  }

  // 2) QK projection in fp8: [4096,2048] x [4096,2048]^T -> qk8 [4096][4096] e4m3
  gemm_qk_fp8<<<dim3(QKN / 128, MTOK / 128), 256, 0, stream>>>(
      x8, wqk8, biasqk, qk8, MTOK, QKN, DD);

  // 3) V projection in bf16 -> v [4096][2048]
  gemm_bt<true><<<dim3(DD / 128, MTOK / 128), 256, 0, stream>>>(
      (const __bf16*)xb, (const __bf16*)wvo, wv_b, v, MTOK, DD, DD);

  // 4) denominators + diagonal exps (fp8 MFMA, work-balanced paired i-tiles)
  qk_rowsum8<<<dim3(16, BHH), 256, 0, stream>>>(
      qk8,            // q at col 0
      qk8 + DD,       // k at col 2048
      denom, diag);

  // 5) V scan -> ctx
  scan_pass1<<<BHH * NCHUNK, 256, 0, stream>>>((const __bf16*)v, csum);
  scan_pass2<<<BHH * NCHUNK, 256, 0, stream>>>((const __bf16*)v, csum,
                                               denom, diag, ctx);

  // 6) output projection: [4096,2048] x [2048,2048]^T -> d_out fp32
  gemm_bt<false><<<dim3(DD / 128, MTOK / 128), 256, 0, stream>>>(
      (const __bf16*)ctx, (const __bf16*)(wvo + (size_t)DD * DD), wo_b,
      d_out, MTOK, DD, DD);
}

// Round 4
// 367.488 us; speedup vs baseline: 1.2106x; 1.0731x over previous
//
#include <hip/hip_runtime.h>

// Problem constants
#define BB 2
#define SS 2048
#define DD 2048
#define HH 16
#define HDIM 128
#define MTOK (BB*SS)     // 4096 token rows
#define BHH (BB*HH)      // 32 (b,h) pairs
#define NCHUNK 16        // scan chunks per (b,h): 2048/128
#define QKN (2*DD)       // fp8 qk row stride (q cols 0..2047, k cols 2048..4095)

typedef __attribute__((ext_vector_type(8))) __bf16 bf16x8;
typedef __attribute__((ext_vector_type(4))) float f32x4;
typedef __attribute__((ext_vector_type(8))) int i32x8;

__device__ __forceinline__ unsigned short f2bf(float f) {
  unsigned u = __float_as_uint(f);
  u += 0x7FFFu + ((u >> 16) & 1u);   // RNE
  return (unsigned short)(u >> 16);
}
__device__ __forceinline__ float bf2f(unsigned short s) {
  return __uint_as_float(((unsigned)s) << 16);
}
__device__ __forceinline__ unsigned char f2e4m3(float f) {
  // HW convert, OCP e4m3fn on gfx950, saturating
  int pk = __builtin_amdgcn_cvt_pk_fp8_f32(f, f, 0, false);
  return (unsigned char)(pk & 0xFF);
}

// async global->LDS, 16B per lane; dst must be wave-uniform base (HW adds lane*16)
#define GLOAD_LDS16(src, dst)                                                   \
  __builtin_amdgcn_global_load_lds(                                             \
      (const void __attribute__((address_space(1)))*)(src),                     \
      (void __attribute__((address_space(3)))*)(dst), 16, 0, 0)

// ---------------- converts ----------------
// x -> bf16 (for V gemm) and fp8 (for QK gemm) in one pass
__global__ void cvt_x_dual(const float* __restrict__ in,
                           unsigned short* __restrict__ outb,
                           unsigned int* __restrict__ out8, int n4) {
  int i = blockIdx.x * blockDim.x + threadIdx.x;
  if (i < n4) {
    float4 v = ((const float4*)in)[i];
    ushort4 o;
    o.x = f2bf(v.x); o.y = f2bf(v.y); o.z = f2bf(v.z); o.w = f2bf(v.w);
    ((ushort4*)outb)[i] = o;
    int p0 = __builtin_amdgcn_cvt_pk_fp8_f32(v.x, v.y, 0, false);
    int p1 = __builtin_amdgcn_cvt_pk_fp8_f32(v.z, v.w, 0, false);
    out8[i] = (unsigned)(p0 & 0xFFFF) | ((unsigned)(p1 & 0xFFFF) << 16);
  }
}

// wq,wk -> fp8 contiguous [2*DD][DD]
__global__ void cvt_wqk8(const float* __restrict__ a, const float* __restrict__ b,
                         unsigned int* __restrict__ out) {
  int i = blockIdx.x * blockDim.x + threadIdx.x;  // < 2<<20
  int sel = i >> 20, r = i & 0xFFFFF;             // DD*DD/4 == 1<<20
  const float* src = sel == 0 ? a : b;
  float4 v = ((const float4*)src)[r];
  int p0 = __builtin_amdgcn_cvt_pk_fp8_f32(v.x, v.y, 0, false);
  int p1 = __builtin_amdgcn_cvt_pk_fp8_f32(v.z, v.w, 0, false);
  out[i] = (unsigned)(p0 & 0xFFFF) | ((unsigned)(p1 & 0xFFFF) << 16);
}

// wv,wo -> bf16, contiguous dest (wv at 0, wo at DD*DD)
__global__ void cvt_w2bf(const float* __restrict__ a, const float* __restrict__ b,
                         unsigned short* __restrict__ out) {
  int i = blockIdx.x * blockDim.x + threadIdx.x;  // < 2<<20
  int sel = i >> 20, r = i & 0xFFFFF;
  const float* src = sel == 0 ? a : b;
  float4 v = ((const float4*)src)[r];
  ushort4 o;
  o.x = f2bf(v.x); o.y = f2bf(v.y); o.z = f2bf(v.z); o.w = f2bf(v.w);
  ((ushort4*)out)[i] = o;
}

__global__ void concat2(const float* __restrict__ a, const float* __restrict__ b,
                        float* __restrict__ out) {
  int i = blockIdx.x * blockDim.x + threadIdx.x;
  if (i < DD) { out[i] = a[i]; out[DD + i] = b[i]; }
}

// ---------------- bf16 GEMM: C[M][N] = A[M][K] @ W[N][K]^T + bias[N] ----------------
// m97-style: 128x128 tile, BK=32, 4 waves 2x2, 16x16x32 bf16 MFMA.
// (round-2 exact form: no swizzle — fragment-read pattern is already bank-uniform)
template <bool OUT_BF16>
__global__ __launch_bounds__(256, 2) void gemm_bt(
    const __bf16* __restrict__ A, const __bf16* __restrict__ W,
    const float* __restrict__ bias, void* __restrict__ Cout,
    int M, int N, int K) {
  __shared__ __bf16 lA[128 * 32];  // 8 KB
  __shared__ __bf16 lB[128 * 32];
  const int t = threadIdx.x;
  const int lane = t & 63, wave = t >> 6;
  const int quad = lane >> 4, l16 = lane & 15;
  const int m0 = blockIdx.y * 128, n0 = blockIdx.x * 128;
  const int wm = (wave & 1) * 64, wn = (wave >> 1) * 64;

  f32x4 acc[4][4] = {};

  for (int k0 = 0; k0 < K; k0 += 32) {
#pragma unroll
    for (int c = 0; c < 2; ++c) {
      int lin = c * 256 + t;          // 16B-chunk id, 4 chunks per 32-col row
      int row = lin >> 2;
      int col = (lin & 3) * 8;
      const __bf16* srcA = A + (size_t)(m0 + row) * K + k0 + col;
      const __bf16* srcB = W + (size_t)(n0 + row) * K + k0 + col;
      GLOAD_LDS16(srcA, &lA[(c * 256 + wave * 64) * 8]);
      GLOAD_LDS16(srcB, &lB[(c * 256 + wave * 64) * 8]);
    }
    __syncthreads();
    bf16x8 af[4], bfr[4];
#pragma unroll
    for (int mt = 0; mt < 4; ++mt)
      af[mt] = *(const bf16x8*)&lA[(wm + mt * 16 + l16) * 32 + quad * 8];
#pragma unroll
    for (int nt = 0; nt < 4; ++nt)
      bfr[nt] = *(const bf16x8*)&lB[(wn + nt * 16 + l16) * 32 + quad * 8];
#pragma unroll
    for (int mt = 0; mt < 4; ++mt)
#pragma unroll
      for (int nt = 0; nt < 4; ++nt)
        acc[mt][nt] = __builtin_amdgcn_mfma_f32_16x16x32_bf16(af[mt], bfr[nt],
                                                              acc[mt][nt], 0, 0, 0);
    __syncthreads();
  }

  // epilogue: C/D layout col=lane&15, row=quad*4+reg  [m89/m91 verified]
#pragma unroll
  for (int mt = 0; mt < 4; ++mt) {
#pragma unroll
    for (int nt = 0; nt < 4; ++nt) {
      int col = n0 + wn + nt * 16 + l16;
      float bv = bias[col];
#pragma unroll
      for (int r = 0; r < 4; ++r) {
        int row = m0 + wm + mt * 16 + quad * 4 + r;
        float v = acc[mt][nt][r] + bv;
        if constexpr (OUT_BF16)
          ((unsigned short*)Cout)[(size_t)row * N + col] = f2bf(v);
        else
          ((float*)Cout)[(size_t)row * N + col] = v;
      }
    }
  }
}

// ---------------- fp8 MX GEMM: C8[M][N] = e4m3( A8 @ W8^T + bias ) ----------------
// 128x128 tile, BK=128, mfma_scale 16x16x128 f8f6f4 with unit scales (e8m0=127):
// bit-identical to non-scaled fp8 but ~2x MFMA rate [m21/m148].
__global__ __launch_bounds__(256, 2) void gemm_qk_fp8(
    const unsigned char* __restrict__ A8, const unsigned char* __restrict__ W8,
    const float* __restrict__ bias, unsigned char* __restrict__ Cout,
    int M, int N, int K) {
  __shared__ unsigned char lA[128 * 128];  // 16 KB, row-major [128][128B]
  __shared__ unsigned char lB[128 * 128];  // 16 KB
  const int t = threadIdx.x;
  const int lane = t & 63, wave = t >> 6;
  const int quad = lane >> 4, l16 = lane & 15;
  const int m0 = blockIdx.y * 128, n0 = blockIdx.x * 128;
  const int wm = (wave & 1) * 64, wn = (wave >> 1) * 64;

  f32x4 acc[4][4] = {};

  for (int k0 = 0; k0 < K; k0 += 128) {
#pragma unroll
    for (int c = 0; c < 4; ++c) {
      int lin = c * 256 + t;          // 16B-chunk id, 1024 per matrix (8/row)
      int row = lin >> 3;
      int ch = lin & 7;
      const unsigned char* srcA = A8 + (size_t)(m0 + row) * K + k0 + ch * 16;
      const unsigned char* srcB = W8 + (size_t)(n0 + row) * K + k0 + ch * 16;
      GLOAD_LDS16(srcA, &lA[(c * 256 + wave * 64) * 16]);
      GLOAD_LDS16(srcB, &lB[(c * 256 + wave * 64) * 16]);
    }
    __syncthreads();
    // fragments: A[m=l16][k=quad*32+j], 32B/lane (one 32-elem MX block -> 1 scale)
    i32x8 af[4];
#pragma unroll
    for (int mt = 0; mt < 4; ++mt)
      af[mt] = *(const i32x8*)&lA[(wm + mt * 16 + l16) * 128 + quad * 32];
#pragma unroll
    for (int nt = 0; nt < 4; ++nt) {
      i32x8 bfr = *(const i32x8*)&lB[(wn + nt * 16 + l16) * 128 + quad * 32];
#pragma unroll
      for (int mt = 0; mt < 4; ++mt)
        acc[mt][nt] = __builtin_amdgcn_mfma_scale_f32_16x16x128_f8f6f4(
            af[mt], bfr, acc[mt][nt], 0 /*fmtA=fp8*/, 0 /*fmtB=fp8*/,
            0, 127 /*scaleA=1.0*/, 0, 127 /*scaleB=1.0*/);
    }
    __syncthreads();
  }

  // epilogue: C/D layout shape-determined, same as 16x16x32 [m121-m128]
#pragma unroll
  for (int mt = 0; mt < 4; ++mt) {
#pragma unroll
    for (int nt = 0; nt < 4; ++nt) {
      int col = n0 + wn + nt * 16 + l16;
      float bv = bias[col];
#pragma unroll
      for (int r = 0; r < 4; ++r) {
        int row = m0 + wm + mt * 16 + quad * 4 + r;
        Cout[(size_t)row * N + col] = f2e4m3(acc[mt][nt][r] + bv);
      }
    }
  }
}

// ---------------- QK^T upper-triangle exp row-sums + diagonal (fp8) ----------------
// Work-balanced: block (p, bh) handles i-tiles p and 31-p (trips sum to 17).
// denom[i] = i + sum_{j>=i} exp(s_ij*scale); diag[i] = exp(s_ii*scale).
__global__ __launch_bounds__(256, 2) void qk_rowsum8(
    const unsigned char* __restrict__ q8, const unsigned char* __restrict__ k8,
    float* __restrict__ denom, float* __restrict__ diag) {
  // LDS layout [ks=4][row=128][32 B]
  __shared__ unsigned char lK[4 * 128 * 32];  // 16 KB
  const int t = threadIdx.x;
  const int lane = t & 63, wave = t >> 6;
  const int quad = lane >> 4, l16 = lane & 15;
  const int bh = blockIdx.y;
  const int b = bh >> 4, h = bh & 15;
  const float scale = 0.02209708691207961f;  // 1/sqrt(2048)

#pragma unroll
  for (int sub = 0; sub < 2; ++sub) {
    const int tile = (sub == 0) ? (int)blockIdx.x : 31 - (int)blockIdx.x;
    const int i0 = tile * 64;
    const int rowg = i0 + wave * 16;

    long long af[4];
    const unsigned char* qbase =
        q8 + (size_t)(b * SS + rowg + l16) * QKN + h * HDIM;
#pragma unroll
    for (int ks = 0; ks < 4; ++ks)
      af[ks] = *(const long long*)(qbase + ks * 32 + quad * 8);

    float rowsum[4] = {0.f, 0.f, 0.f, 0.f};
    float diagv[4] = {0.f, 0.f, 0.f, 0.f};

    for (int j0 = i0 & ~127; j0 < SS; j0 += 128) {
      // stage K-tile [128 rows][128 B] into [ks][row][32 B]
#pragma unroll
      for (int c = 0; c < 4; ++c) {
        int L = c * 256 + t;        // 16B-chunk id, 1024 total
        int ks = L >> 8;            // 256 chunks per ks-slice
        int rem = L & 255;
        int row = rem >> 1;
        int c2 = rem & 1;
        const unsigned char* src =
            k8 + (size_t)(b * SS + j0 + row) * QKN + h * HDIM + ks * 32 + c2 * 16;
        GLOAD_LDS16(src, &lK[(c * 256 + wave * 64) * 16]);
      }
      __syncthreads();
#pragma unroll
      for (int nt = 0; nt < 8; ++nt) {
        f32x4 acc = {0.f, 0.f, 0.f, 0.f};
#pragma unroll
        for (int ks = 0; ks < 4; ++ks) {
          long long bfr =
              *(const long long*)&lK[ks * 4096 + (nt * 16 + l16) * 32 + quad * 8];
          acc = __builtin_amdgcn_mfma_f32_16x16x32_fp8_fp8(af[ks], bfr, acc, 0, 0, 0);
        }
        int colg = j0 + nt * 16 + l16;
#pragma unroll
        for (int r = 0; r < 4; ++r) {
          int rg = rowg + quad * 4 + r;
          if (colg >= rg) {
            float e = __expf(acc[r] * scale);
            rowsum[r] += e;
            if (colg == rg) diagv[r] = e;
          }
        }
      }
      __syncthreads();
    }

#pragma unroll
    for (int r = 0; r < 4; ++r) {
      float s = rowsum[r], d = diagv[r];
#pragma unroll
      for (int off = 1; off < 16; off <<= 1) {
        s += __shfl_xor(s, off, 64);
        d += __shfl_xor(d, off, 64);
      }
      if (l16 == 0) {
        int rg = rowg + quad * 4 + r;
        denom[bh * SS + rg] = (float)rg + s;
        diag[bh * SS + rg] = d;
      }
    }
  }
}

// ---------------- V prefix-scan, two-pass, 16B/lane ----------------
// v is a dedicated [MTOK][DD] bf16 buffer.
__global__ void scan_pass1(const __bf16* __restrict__ v0,
                           float* __restrict__ csum) {
  int blk = blockIdx.x;
  int bh = blk >> 4, c = blk & 15;
  int b = bh >> 4, h = bh & 15;
  int t = threadIdx.x;
  int rs = t >> 4, dg = t & 15;
  const unsigned short* base = (const unsigned short*)v0 +
      (size_t)(b * SS + c * 128 + rs * 8) * DD + h * HDIM + dg * 8;
  float s[8] = {0.f, 0.f, 0.f, 0.f, 0.f, 0.f, 0.f, 0.f};
#pragma unroll
  for (int i = 0; i < 8; ++i) {
    uint4 u = *(const uint4*)(base + (size_t)i * DD);
    const unsigned short* us = (const unsigned short*)&u;
#pragma unroll
    for (int j = 0; j < 8; ++j) s[j] += bf2f(us[j]);
  }
  __shared__ float red[16 * 128];
#pragma unroll
  for (int j = 0; j < 8; ++j) red[rs * 128 + dg * 8 + j] = s[j];
  __syncthreads();
  for (int st = 8; st >= 1; st >>= 1) {
    if (rs < st) {
#pragma unroll
      for (int j = 0; j < 8; ++j)
        red[rs * 128 + dg * 8 + j] += red[(rs + st) * 128 + dg * 8 + j];
    }
    __syncthreads();
  }
  if (rs == 0) {
#pragma unroll
    for (int j = 0; j < 8; ++j)
      csum[(size_t)blk * 128 + dg * 8 + j] = red[dg * 8 + j];
  }
}

__global__ void scan_pass2(const __bf16* __restrict__ v0,
                           const float* __restrict__ csum,
                           const float* __restrict__ denom,
                           const float* __restrict__ diag,
                           unsigned short* __restrict__ ctx) {
  int blk = blockIdx.x;
  int bh = blk >> 4, c = blk & 15;
  int b = bh >> 4, h = bh & 15;
  int t = threadIdx.x;
  int rs = t >> 4, dg = t & 15;
  const unsigned short* vbase = (const unsigned short*)v0 +
      (size_t)(b * SS + c * 128 + rs * 8) * DD + h * HDIM + dg * 8;
  float vrow[8][8];
  float ls[8] = {0.f, 0.f, 0.f, 0.f, 0.f, 0.f, 0.f, 0.f};
#pragma unroll
  for (int i = 0; i < 8; ++i) {
    uint4 u = *(const uint4*)(vbase + (size_t)i * DD);
    const unsigned short* us = (const unsigned short*)&u;
#pragma unroll
    for (int j = 0; j < 8; ++j) {
      vrow[i][j] = bf2f(us[j]);
      ls[j] += vrow[i][j];
    }
  }
  __shared__ float red[16 * 128];
#pragma unroll
  for (int j = 0; j < 8; ++j) red[rs * 128 + dg * 8 + j] = ls[j];
  __syncthreads();

  float pre[8] = {0.f, 0.f, 0.f, 0.f, 0.f, 0.f, 0.f, 0.f};
  for (int cc = 0; cc < c; ++cc) {
    const float* cp = csum + (size_t)(bh * 16 + cc) * 128 + dg * 8;
#pragma unroll
    for (int j = 0; j < 8; ++j) pre[j] += cp[j];
  }
  for (int ss2 = 0; ss2 < rs; ++ss2) {
#pragma unroll
    for (int j = 0; j < 8; ++j) pre[j] += red[ss2 * 128 + dg * 8 + j];
  }

  int row0 = c * 128 + rs * 8;
  unsigned short* obase =
      ctx + (size_t)(b * SS + row0) * DD + h * HDIM + dg * 8;
  const float* dn = denom + bh * SS + row0;
  const float* dgp = diag + bh * SS + row0;
#pragma unroll
  for (int i = 0; i < 8; ++i) {
    float inv = 1.0f / dn[i];
    float dv = dgp[i];
    unsigned short o[8];
#pragma unroll
    for (int j = 0; j < 8; ++j) {
      float val = (pre[j] + dv * vrow[i][j]) * inv;
      o[j] = f2bf(val);
      pre[j] += vrow[i][j];
    }
    *(uint4*)(obase + (size_t)i * DD) = *(const uint4*)o;
  }
}

extern "C" void kernel_launch(void* const* d_in, const int* in_sizes, int n_in,
                              void* d_out, int out_size, void* d_ws, size_t ws_size,
                              hipStream_t stream) {
  (void)in_sizes; (void)n_in; (void)out_size; (void)ws_size;
  const float* x    = (const float*)d_in[0];
  const float* wq_w = (const float*)d_in[1];
  const float* wq_b = (const float*)d_in[2];
  const float* wk_w = (const float*)d_in[3];
  const float* wk_b = (const float*)d_in[4];
  const float* wv_w = (const float*)d_in[5];
  const float* wv_b = (const float*)d_in[6];
  const float* wo_w = (const float*)d_in[7];
  const float* wo_b = (const float*)d_in[8];

  char* ws = (char*)d_ws;
  size_t off = 0;
  auto alloc = [&](size_t bytes) {
    char* p = ws + off;
    off += (bytes + 255) & ~(size_t)255;
    return p;
  };
  unsigned short* xb   = (unsigned short*)alloc((size_t)MTOK * DD * 2);    // 16 MB
  unsigned char*  x8   = (unsigned char*)alloc((size_t)MTOK * DD);         // 8 MB
  unsigned char*  wqk8 = (unsigned char*)alloc((size_t)2 * DD * DD);       // 8 MB
  unsigned short* wvo  = (unsigned short*)alloc((size_t)2 * DD * DD * 2);  // 16 MB (wv | wo)
  unsigned char*  qk8  = (unsigned char*)alloc((size_t)MTOK * QKN);        // 16 MB
  unsigned short* v    = (unsigned short*)alloc((size_t)MTOK * DD * 2);    // 16 MB
  unsigned short* ctx  = (unsigned short*)alloc((size_t)MTOK * DD * 2);    // 16 MB
  float* biasqk = (float*)alloc((size_t)2 * DD * 4);
  float* denom  = (float*)alloc((size_t)BHH * SS * 4);
  float* diag   = (float*)alloc((size_t)BHH * SS * 4);
  float* csum   = (float*)alloc((size_t)BHH * NCHUNK * 128 * 4);

  // 1) converts
  {
    int n4 = MTOK * DD / 4;
    cvt_x_dual<<<n4 / 256, 256, 0, stream>>>(x, xb, (unsigned int*)x8, n4);
    cvt_wqk8<<<(2 << 20) / 256, 256, 0, stream>>>(wq_w, wk_w, (unsigned int*)wqk8);
    cvt_w2bf<<<(2 << 20) / 256, 256, 0, stream>>>(wv_w, wo_w, wvo);
    concat2<<<(DD + 255) / 256, 256, 0, stream>>>(wq_b, wk_b, biasqk);
  }

  // 2) QK projection, MX-fp8: [4096,2048] x [4096,2048]^T -> qk8 [4096][4096] e4m3
  gemm_qk_fp8<<<dim3(QKN / 128, MTOK / 128), 256, 0, stream>>>(
      x8, wqk8, biasqk, qk8, MTOK, QKN, DD);

  // 3) V projection in bf16 -> v [4096][2048]
  gemm_bt<true><<<dim3(DD / 128, MTOK / 128), 256, 0, stream>>>(
      (const __bf16*)xb, (const __bf16*)wvo, wv_b, v, MTOK, DD, DD);

  // 4) denominators + diagonal exps (fp8 MFMA, work-balanced paired i-tiles)
  qk_rowsum8<<<dim3(16, BHH), 256, 0, stream>>>(
      qk8,            // q at col 0
      qk8 + DD,       // k at col 2048
      denom, diag);

  // 5) V scan -> ctx
  scan_pass1<<<BHH * NCHUNK, 256, 0, stream>>>((const __bf16*)v, csum);
  scan_pass2<<<BHH * NCHUNK, 256, 0, stream>>>((const __bf16*)v, csum,
                                               denom, diag, ctx);

  // 6) output projection: [4096,2048] x [2048,2048]^T -> d_out fp32
  gemm_bt<false><<<dim3(DD / 128, MTOK / 128), 256, 0, stream>>>(
      (const __bf16*)ctx, (const __bf16*)(wvo + (size_t)DD * DD), wo_b,
      d_out, MTOK, DD, DD);
}